// Round 1
// baseline (208.597 us; speedup 1.0000x reference)
//
#include <hip/hip_runtime.h>
#include <hip/hip_bf16.h>
#include <cstdint>

#define RST 16777216  // 4096*4096 floats per rating class

// ---------------------------------------------------------------------------
// K1: label extraction. One block per batch-row i. Stage the full 16KB rating
// row (per class) in LDS coalesced, then gather at v[j]. L[i,j] in {0..4}, 5=unrated.
// ---------------------------------------------------------------------------
__global__ __launch_bounds__(256) void k_labels(const int* __restrict__ u, const int* __restrict__ v,
                                                const float* __restrict__ ratings, unsigned char* __restrict__ L){
  __shared__ float row[4096];
  int i = blockIdx.x;
  int tid = threadIdx.x;
  int U = u[i];
  int j0 = tid * 8;
  int vj[8];
#pragma unroll
  for (int k = 0; k < 8; k++) vj[k] = v[j0 + k];
  int lab[8];
#pragma unroll
  for (int k = 0; k < 8; k++) lab[k] = 5;
  const float* rbase = ratings + (size_t)U * 4096;
  for (int c = 0; c < 5; c++){
    const float4* src = (const float4*)(rbase + (size_t)c * RST);
#pragma unroll
    for (int k = 0; k < 4; k++) ((float4*)row)[tid + k*256] = src[tid + k*256];
    __syncthreads();
#pragma unroll
    for (int k = 0; k < 8; k++) if (row[vj[k]] > 0.5f) lab[k] = c;
    __syncthreads();
  }
  unsigned int lo = 0, hi = 0;
#pragma unroll
  for (int k = 0; k < 4; k++){ lo |= ((unsigned)lab[k]) << (8*k); hi |= ((unsigned)lab[k+4]) << (8*k); }
  *(uint2*)(L + (size_t)i * 2048 + j0) = make_uint2(lo, hi);
}

// ---------------------------------------------------------------------------
// K2: byte transpose L -> LT (64x64 tiles via LDS)
// ---------------------------------------------------------------------------
__global__ __launch_bounds__(256) void k_transpose(const unsigned char* __restrict__ L, unsigned char* __restrict__ LT){
  __shared__ unsigned char tile[64][64];
  int i0 = blockIdx.y * 64, j0 = blockIdx.x * 64;
  int tid = threadIdx.x;
  int r = tid >> 2, cq = tid & 3;
  uint4 d = *(const uint4*)(L + (size_t)(i0 + r) * 2048 + j0 + cq * 16);
  *(uint4*)&tile[r][cq * 16] = d;
  __syncthreads();
  unsigned char ob[16];
#pragma unroll
  for (int k = 0; k < 16; k++) ob[k] = tile[cq * 16 + k][r];
  *(uint4*)(LT + (size_t)(j0 + r) * 2048 + i0 + cq * 16) = *(uint4*)ob;
}

// ---------------------------------------------------------------------------
// K3: row counts. side 0: di[r] = labeled count in L row r (+ n_obs). side 1: du[r] from LT.
// ---------------------------------------------------------------------------
__global__ __launch_bounds__(256) void k_counts(const unsigned char* __restrict__ L, const unsigned char* __restrict__ LT,
                                                int* __restrict__ di, int* __restrict__ du, int* __restrict__ n_obs){
  int r = blockIdx.x;
  int side = blockIdx.y;
  const unsigned char* base = side ? LT : L;
  uint2 d = ((const uint2*)(base + (size_t)r * 2048))[threadIdx.x];
  int cnt = 0;
#pragma unroll
  for (int k = 0; k < 4; k++){ cnt += (((d.x >> (8*k)) & 255) != 5); cnt += (((d.y >> (8*k)) & 255) != 5); }
#pragma unroll
  for (int o = 32; o > 0; o >>= 1) cnt += __shfl_down(cnt, o);
  __shared__ int wsum[4];
  int wid = threadIdx.x >> 6, lane = threadIdx.x & 63;
  if (lane == 0) wsum[wid] = cnt;
  __syncthreads();
  if (threadIdx.x == 0){
    int tot = wsum[0] + wsum[1] + wsum[2] + wsum[3];
    if (side == 0){ di[r] = tot; atomicAdd(n_obs, tot); } else du[r] = tot;
  }
}

// ---------------------------------------------------------------------------
// K4: support S[c][n][h] = x[n,:] . gc_w[c,:,h]   (n<2048: ue; else ve)
// One wave per 16 rows; weight column held in 64 VGPRs; x broadcast via shfl.
// ---------------------------------------------------------------------------
__global__ __launch_bounds__(256) void k_support(const int* __restrict__ u, const int* __restrict__ v,
    const float* __restrict__ u_emb, const float* __restrict__ v_emb, const float* __restrict__ gc_w,
    float* __restrict__ S){
  int c = blockIdx.y;
  int lane = threadIdx.x & 63;
  int wid = threadIdx.x >> 6;
  int n0 = blockIdx.x * 64 + wid * 16;
  float w[64];
#pragma unroll
  for (int d = 0; d < 64; d++) w[d] = gc_w[c * 4096 + d * 64 + lane];
  for (int k = 0; k < 16; k++){
    int n = n0 + k;
    int idx = (n < 2048) ? u[n] : v[n - 2048];
    const float* xr = (n < 2048) ? (u_emb + (size_t)idx * 64) : (v_emb + (size_t)idx * 64);
    float xv = xr[lane];
    float acc = 0.f;
#pragma unroll
    for (int d = 0; d < 64; d++) acc += __shfl(xv, d) * w[d];
    S[((size_t)c * 4096 + n) * 64 + lane] = acc;
  }
}

// ---------------------------------------------------------------------------
// K5: sparse aggregate. Row r<2048: aggsum_u[r,h] = sum over labeled j of S[c][2048+j][h].
//     Row r>=2048: scan LT row, operand S[c][i][h]. 4 waves split the 2048-scan.
// ---------------------------------------------------------------------------
__global__ __launch_bounds__(256) void k_agg(const unsigned char* __restrict__ L, const unsigned char* __restrict__ LT,
    const float* __restrict__ S, float* __restrict__ aggsum){
  int r = blockIdx.x;
  int wid = threadIdx.x >> 6, lane = threadIdx.x & 63;
  bool uside = (r < 2048);
  const unsigned char* rowp = uside ? (L + (size_t)r * 2048) : (LT + (size_t)(r - 2048) * 2048);
  const float* Sop = S + (uside ? 131072 : 0) + lane;
  float acc = 0.f;
  const uint4* rp = (const uint4*)rowp;
  for (int it = 0; it < 32; it++){
    uint4 dd = rp[wid * 32 + it];
    int jb = wid * 512 + it * 16;
#define PROCW(word, jo) { unsigned int w_ = (word); \
    int c0 = w_ & 255, c1 = (w_ >> 8) & 255, c2 = (w_ >> 16) & 255, c3 = (w_ >> 24); \
    if (c0 != 5) acc += Sop[(size_t)c0 * 262144 + (size_t)(jb + (jo) + 0) * 64]; \
    if (c1 != 5) acc += Sop[(size_t)c1 * 262144 + (size_t)(jb + (jo) + 1) * 64]; \
    if (c2 != 5) acc += Sop[(size_t)c2 * 262144 + (size_t)(jb + (jo) + 2) * 64]; \
    if (c3 != 5) acc += Sop[(size_t)c3 * 262144 + (size_t)(jb + (jo) + 3) * 64]; }
    PROCW(dd.x, 0) PROCW(dd.y, 4) PROCW(dd.z, 8) PROCW(dd.w, 12)
#undef PROCW
  }
  __shared__ float red[4][64];
  red[wid][lane] = acc;
  __syncthreads();
  if (wid == 0) aggsum[(size_t)r * 64 + lane] = red[0][lane] + red[1][lane] + red[2][lane] + red[3][lane];
}

// ---------------------------------------------------------------------------
// K6: z = relu(inv_count * aggsum + sum_c gc_b); hidden = sigmoid(z @ dense_w + dense_b)
// NOTE reference quirk: rows <2048 (users) use du (COLUMN counts), rows >=2048 use di.
// ---------------------------------------------------------------------------
__global__ __launch_bounds__(256) void k_hidden(const float* __restrict__ aggsum, const int* __restrict__ du, const int* __restrict__ di,
    const float* __restrict__ gc_b, const float* __restrict__ dense_w, const float* __restrict__ dense_b,
    float* __restrict__ hidden){
  int wid = threadIdx.x >> 6, lane = threadIdx.x & 63;
  int r = blockIdx.x * 4 + wid;
  float a = aggsum[(size_t)r * 64 + lane];
  int cnt = (r < 2048) ? du[r] : di[r - 2048];
  float inv = (cnt > 0) ? (1.0f / (float)cnt) : 0.0f;
  float bsum = 0.f;
#pragma unroll
  for (int c = 0; c < 5; c++) bsum += gc_b[c * 64 + lane];
  float z = fmaxf(a * inv + bsum, 0.f);
  __shared__ float zb[4][64];
  zb[wid][lane] = z;
  __syncthreads();
  if (lane < 32){
    float s = dense_b[lane];
#pragma unroll
    for (int h = 0; h < 64; h++) s += zb[wid][h] * dense_w[h * 32 + lane];
    hidden[(size_t)r * 32 + lane] = 1.0f / (1.0f + __expf(-s));
  }
}

// ---------------------------------------------------------------------------
// K7: t[c][i][e] = hu[i,:] . dec_w[c,:,e]
// ---------------------------------------------------------------------------
__global__ __launch_bounds__(256) void k_dec(const float* __restrict__ hidden, const float* __restrict__ dec_w, float* __restrict__ t){
  int gp = blockIdx.x * 8 + (threadIdx.x >> 5);
  int e = threadIdx.x & 31;
  int c = gp >> 11, i = gp & 2047;
  const float* hr = hidden + (size_t)i * 32;
  const float* wc = dec_w + (size_t)c * 1024 + e;
  float s = 0.f;
#pragma unroll
  for (int d = 0; d < 32; d++) s += hr[d] * wc[d * 32];
  t[(size_t)gp * 32 + e] = s;
}

// ---------------------------------------------------------------------------
// K8: fused logits -> softmax -> m_hat + loss + accuracy. Tile: 16 i x 512 j per block,
// 2 j per thread. t-tile (5x16x32 f32 = 10KB) in LDS, hv rows in registers.
// ---------------------------------------------------------------------------
#define EPI(l, lab, outp) do{ \
  float mx = fmaxf(fmaxf(fmaxf(l[0], l[1]), fmaxf(l[2], l[3])), l[4]); \
  float e0 = __expf(l[0]-mx), e1 = __expf(l[1]-mx), e2 = __expf(l[2]-mx), e3 = __expf(l[3]-mx), e4 = __expf(l[4]-mx); \
  float ssum = e0 + e1 + e2 + e3 + e4; \
  *(outp) = (e1 + 2.f*e2 + 3.f*e3 + 4.f*e4) / ssum; \
  if ((lab) < 5){ \
    int pred = 0; float bm = l[0]; \
    if (l[1] > bm){ bm = l[1]; pred = 1; } \
    if (l[2] > bm){ bm = l[2]; pred = 2; } \
    if (l[3] > bm){ bm = l[3]; pred = 3; } \
    if (l[4] > bm){ bm = l[4]; pred = 4; } \
    float ll = (lab)==0 ? l[0] : ((lab)==1 ? l[1] : ((lab)==2 ? l[2] : ((lab)==3 ? l[3] : l[4]))); \
    lsum += __logf(ssum) + mx - ll; \
    acnt += (pred == (lab)); \
  } \
}while(0)

__global__ __launch_bounds__(256) void k_logits(const float* __restrict__ t, const float* __restrict__ hidden,
    const unsigned char* __restrict__ L, float* __restrict__ mhat, float* __restrict__ loss_sum, int* __restrict__ acc_cnt){
  __shared__ float ts[2560];
  int tid = threadIdx.x;
  int i0 = blockIdx.y * 16;
  int ja = blockIdx.x * 512 + tid;
  int jb = ja + 256;
  const float* hv = hidden + 2048 * 32;
  for (int idx = tid; idx < 640; idx += 256){
    int c = idx >> 7, rem = idx & 127;
    ((float4*)ts)[c * 128 + rem] = ((const float4*)t)[((size_t)(c * 2048 + i0)) * 8 + rem];
  }
  float hva[32], hvb[32];
#pragma unroll
  for (int q = 0; q < 8; q++){
    *(float4*)&hva[q * 4] = *(const float4*)(hv + (size_t)ja * 32 + q * 4);
    *(float4*)&hvb[q * 4] = *(const float4*)(hv + (size_t)jb * 32 + q * 4);
  }
  __syncthreads();
  float lsum = 0.f; int acnt = 0;
  for (int ii = 0; ii < 16; ii++){
    int i = i0 + ii;
    float la[5], lb[5];
#pragma unroll
    for (int c = 0; c < 5; c++){
      const float4* tsr = (const float4*)(ts + (c * 16 + ii) * 32);
      float sa = 0.f, sb = 0.f;
#pragma unroll
      for (int q = 0; q < 8; q++){
        float4 tv = tsr[q];
        sa += tv.x * hva[q*4+0]; sa += tv.y * hva[q*4+1]; sa += tv.z * hva[q*4+2]; sa += tv.w * hva[q*4+3];
        sb += tv.x * hvb[q*4+0]; sb += tv.y * hvb[q*4+1]; sb += tv.z * hvb[q*4+2]; sb += tv.w * hvb[q*4+3];
      }
      la[c] = sa; lb[c] = sb;
    }
    int laba = L[(size_t)i * 2048 + ja];
    int labb = L[(size_t)i * 2048 + jb];
    EPI(la, laba, mhat + (size_t)i * 2048 + ja);
    EPI(lb, labb, mhat + (size_t)i * 2048 + jb);
  }
#pragma unroll
  for (int o = 32; o > 0; o >>= 1){ lsum += __shfl_down(lsum, o); acnt += __shfl_down(acnt, o); }
  __shared__ float wl[4]; __shared__ int wa[4];
  int wid = tid >> 6, lane = tid & 63;
  if (lane == 0){ wl[wid] = lsum; wa[wid] = acnt; }
  __syncthreads();
  if (tid == 0){ atomicAdd(loss_sum, wl[0] + wl[1] + wl[2] + wl[3]); atomicAdd(acc_cnt, wa[0] + wa[1] + wa[2] + wa[3]); }
}

// ---------------------------------------------------------------------------
// K9: finalize scalars
// ---------------------------------------------------------------------------
__global__ void k_final(const float* __restrict__ loss_sum, const int* __restrict__ acc_cnt,
                        const int* __restrict__ n_obs, float* __restrict__ out){
  float n = fmaxf((float)(*n_obs), 1.0f);
  out[0] = (*loss_sum) / n;
  out[1] = ((float)(*acc_cnt)) / n;
}

extern "C" void kernel_launch(void* const* d_in, const int* in_sizes, int n_in,
                              void* d_out, int out_size, void* d_ws, size_t ws_size,
                              hipStream_t stream){
  const int*   u       = (const int*)d_in[0];
  const int*   v       = (const int*)d_in[1];
  const float* ratings = (const float*)d_in[2];
  const float* u_emb   = (const float*)d_in[3];
  const float* v_emb   = (const float*)d_in[4];
  const float* gc_w    = (const float*)d_in[5];
  const float* gc_b    = (const float*)d_in[6];
  const float* dense_w = (const float*)d_in[7];
  const float* dense_b = (const float*)d_in[8];
  const float* dec_w   = (const float*)d_in[9];
  float* out = (float*)d_out;
  char* ws = (char*)d_ws;

  unsigned char* L   = (unsigned char*)(ws + 0);          // 4 MB
  unsigned char* LT  = (unsigned char*)(ws + 4194304);    // 4 MB
  float* S           = (float*)(ws + 8388608);            // 5 MB: [5][4096][64]
  float* aggsum      = (float*)(ws + 13631488);           // 1 MB: [4096][64]
  float* hidden      = (float*)(ws + 14680064);           // 512 KB: [4096][32]
  float* t           = (float*)(ws + 15204352);           // 1.25 MB: [5][2048][32]
  int*   du          = (int*)(ws + 16515072);             // 8 KB
  int*   di          = (int*)(ws + 16523264);             // 8 KB
  float* loss_sum    = (float*)(ws + 16531456);
  int*   acc_cnt     = (int*)(ws + 16531460);
  int*   n_obs       = (int*)(ws + 16531464);

  hipMemsetAsync(ws + 16531456, 0, 12, stream);
  k_labels   <<<2048, 256, 0, stream>>>(u, v, ratings, L);
  k_transpose<<<dim3(32, 32), 256, 0, stream>>>(L, LT);
  k_counts   <<<dim3(2048, 2), 256, 0, stream>>>(L, LT, di, du, n_obs);
  k_support  <<<dim3(64, 5), 256, 0, stream>>>(u, v, u_emb, v_emb, gc_w, S);
  k_agg      <<<4096, 256, 0, stream>>>(L, LT, S, aggsum);
  k_hidden   <<<1024, 256, 0, stream>>>(aggsum, du, di, gc_b, dense_w, dense_b, hidden);
  k_dec      <<<1280, 256, 0, stream>>>(hidden, dec_w, t);
  k_logits   <<<dim3(4, 128), 256, 0, stream>>>(t, hidden, L, out, loss_sum, acc_cnt);
  k_final    <<<1, 1, 0, stream>>>(loss_sum, acc_cnt, n_obs, out + 4194304);
}